// Round 6
// baseline (619.979 us; speedup 1.0000x reference)
//
#include <hip/hip_runtime.h>
#include <math.h>

namespace {

constexpr int NN = 20000;   // nodes
constexpr int NE = 400000;  // edges

constexpr float RS8   = 0.35355339059327373f;  // 1/sqrt(8)
constexpr float RS128 = 0.08838834764831845f;  // 1/sqrt(128)

__device__ __forceinline__ float silu_f(float x) {
    return x / (1.0f + __expf(-x));
}

// pack two floats as bf16 pair (RNE) into one uint
__device__ __forceinline__ unsigned int bf2(float a, float b) {
    unsigned int ua = __float_as_uint(a), ub = __float_as_uint(b);
    ua = (ua + 0x7FFFu + ((ua >> 16) & 1u)) >> 16;
    ub = (ub + 0x7FFFu + ((ub >> 16) & 1u)) >> 16;
    return (ub << 16) | ua;
}
__device__ __forceinline__ float bflo(unsigned int u) { return __uint_as_float(u << 16); }
__device__ __forceinline__ float bfhi(unsigned int u) { return __uint_as_float(u & 0xFFFF0000u); }

// ---------------- node + hist kernel: sc, nf, qk, counts ----------------
__global__ __launch_bounds__(256) void node_hist_kernel(
    const float* __restrict__ node_input, const float* __restrict__ node_attr,
    const int* __restrict__ edge_dst,
    const float* __restrict__ W_sc, const float* __restrict__ W_lin1,
    const float* __restrict__ W_hq, const float* __restrict__ W_dot,
    float* __restrict__ nf_out, float* __restrict__ qk_out, float* __restrict__ sc_out,
    int* __restrict__ counts)
{
    // histogram part (all blocks)
    int e = blockIdx.x * 256 + threadIdx.x;
    if (e < NE) atomicAdd(&counts[edge_dst[e]], 1);

    // node part (first 79 blocks only)
    if (blockIdx.x >= (NN + 255) / 256) return;

    __shared__ float sWsc[2048];   // [a][b][c] (16,8,16), scale folded
    __shared__ float sW1[256];     // [a][c] (16,16)
    __shared__ float sWq[128];     // [a][c] (16,8)
    __shared__ float sdot[64];     // [a][c] (8,8)
    for (int i = threadIdx.x; i < 2048; i += 256) sWsc[i] = W_sc[i] * RS128;
    if (threadIdx.x < 256) sW1[threadIdx.x] = W_lin1[threadIdx.x] * 0.25f;
    if (threadIdx.x < 128) sWq[threadIdx.x] = W_hq[threadIdx.x] * 0.25f;
    if (threadIdx.x < 64)  sdot[threadIdx.x] = W_dot[threadIdx.x] * 0.125f;  // 1/sqrt(64)
    __syncthreads();

    int n = blockIdx.x * 256 + threadIdx.x;
    if (n >= NN) return;

    float ni[16], na[8];
    {
        const float4* p = (const float4*)(node_input + (size_t)n * 16);
        #pragma unroll
        for (int j = 0; j < 4; ++j) {
            float4 t = p[j];
            ni[4*j+0]=t.x; ni[4*j+1]=t.y; ni[4*j+2]=t.z; ni[4*j+3]=t.w;
        }
        const float4* pa = (const float4*)(node_attr + (size_t)n * 8);
        #pragma unroll
        for (int j = 0; j < 2; ++j) {
            float4 t = pa[j];
            na[4*j+0]=t.x; na[4*j+1]=t.y; na[4*j+2]=t.z; na[4*j+3]=t.w;
        }
    }

    float sc[16];
    #pragma unroll
    for (int c = 0; c < 16; ++c) sc[c] = 0.f;
    #pragma unroll 4
    for (int a = 0; a < 16; ++a) {
        #pragma unroll
        for (int b = 0; b < 8; ++b) {
            float p = ni[a] * na[b];
            const float* w = &sWsc[(a * 8 + b) * 16];
            #pragma unroll
            for (int c = 0; c < 16; ++c) sc[c] += p * w[c];
        }
    }

    float nf[16];
    #pragma unroll
    for (int c = 0; c < 16; ++c) {
        float t = 0.f;
        #pragma unroll
        for (int a = 0; a < 16; ++a) t += ni[a] * sW1[a * 16 + c];
        nf[c] = t;
    }
    float q[8];
    #pragma unroll
    for (int c = 0; c < 8; ++c) {
        float t = 0.f;
        #pragma unroll
        for (int a = 0; a < 16; ++a) t += nf[a] * sWq[a * 8 + c];
        q[c] = t;
    }
    float qk[8];
    #pragma unroll
    for (int c = 0; c < 8; ++c) {
        float t = 0.f;
        #pragma unroll
        for (int a = 0; a < 8; ++a) t += q[a] * sdot[a * 8 + c];
        qk[c] = t;
    }

    float4* nfo = (float4*)(nf_out + (size_t)n * 16);
    #pragma unroll
    for (int j = 0; j < 4; ++j) nfo[j] = make_float4(nf[4*j], nf[4*j+1], nf[4*j+2], nf[4*j+3]);
    float4* qko = (float4*)(qk_out + (size_t)n * 8);
    #pragma unroll
    for (int j = 0; j < 2; ++j) qko[j] = make_float4(qk[4*j], qk[4*j+1], qk[4*j+2], qk[4*j+3]);
    float4* sco = (float4*)(sc_out + (size_t)n * 16);
    #pragma unroll
    for (int j = 0; j < 4; ++j) sco[j] = make_float4(sc[4*j], sc[4*j+1], sc[4*j+2], sc[4*j+3]);
}

// ---------------- scan: exclusive prefix of counts -> offs ----------------
__global__ __launch_bounds__(1024) void scan_kernel(
    const int* __restrict__ counts, int* __restrict__ offs)
{
    __shared__ int part[1024];
    int t = threadIdx.x;
    int base = t * 20;
    int s = 0;
    #pragma unroll 4
    for (int i = 0; i < 20; ++i) {
        int idx = base + i;
        if (idx < NN) s += counts[idx];
    }
    part[t] = s;
    __syncthreads();
    #pragma unroll
    for (int d = 1; d < 1024; d <<= 1) {
        int v = (t >= d) ? part[t - d] : 0;
        __syncthreads();
        part[t] += v;
        __syncthreads();
    }
    int run = part[t] - s;
    for (int i = 0; i < 20; ++i) {
        int idx = base + i;
        if (idx < NN) {
            offs[idx] = run;
            run += counts[idx];
        }
    }
}

// ---------------- placement: pos[e] = slot; offs becomes inclusive ----------------
__global__ __launch_bounds__(256) void place_kernel(
    const int* __restrict__ edge_dst, int* __restrict__ offs, int* __restrict__ pos)
{
    int e = blockIdx.x * 256 + threadIdx.x;
    if (e >= NE) return;
    int dst = edge_dst[e];
    pos[e] = atomicAdd(&offs[dst], 1);
}

// ---------------- MLP hiddens with transposed weights ----------------
__device__ __forceinline__ void mlp_hidden_t(const float es[16], const float* __restrict__ w0t,
                                             const float* __restrict__ w1t, const float* __restrict__ w2t,
                                             float out[8])
{
    float h0[8];
    #pragma unroll
    for (int j = 0; j < 8; ++j) {
        float t = 0.f;
        #pragma unroll
        for (int i = 0; i < 16; ++i) t += es[i] * w0t[j * 16 + i];
        h0[j] = silu_f(t);
    }
    float h1[8];
    #pragma unroll
    for (int j = 0; j < 8; ++j) {
        float t = 0.f;
        #pragma unroll
        for (int i = 0; i < 8; ++i) t += h0[i] * w1t[j * 8 + i];
        h1[j] = silu_f(t);
    }
    #pragma unroll
    for (int j = 0; j < 8; ++j) {
        float t = 0.f;
        #pragma unroll
        for (int i = 0; i < 8; ++i) t += h1[i] * w2t[j * 8 + i];
        out[j] = silu_f(t);
    }
}

// ---------------- A: MLP pass (natural edge order, coalesced reads) ----------------
// blob[slot] (64B): [0..3] hk bf16x2, [4..7] hv bf16x2, [8..11] ea f32, [12] src bits
__global__ __launch_bounds__(256) void edge_mlp_kernel(
    const int* __restrict__ pos, const int* __restrict__ edge_src,
    const float* __restrict__ edge_attr, const float* __restrict__ edge_scalars,
    const float* __restrict__ fck_w0, const float* __restrict__ fck_w1,
    const float* __restrict__ fck_w2,
    const float* __restrict__ fcv_w0, const float* __restrict__ fcv_w1,
    const float* __restrict__ fcv_w2,
    float* __restrict__ blob)
{
    __shared__ float sk0t[128], sk1t[64], sk2t[64];
    __shared__ float sv0t[128], sv1t[64], sv2t[64];
    int tid = threadIdx.x;
    for (int i = tid; i < 128; i += 256) { int r = i >> 3, c = i & 7; sk0t[c*16+r] = fck_w0[i] * 0.25f; }
    for (int i = tid; i < 64;  i += 256) { int r = i >> 3, c = i & 7; sk1t[c*8+r]  = fck_w1[i] * RS8; }
    for (int i = tid; i < 64;  i += 256) { int r = i >> 3, c = i & 7; sk2t[c*8+r]  = fck_w2[i] * RS8; }
    for (int i = tid; i < 128; i += 256) { int r = i >> 3, c = i & 7; sv0t[c*16+r] = fcv_w0[i] * 0.25f; }
    for (int i = tid; i < 64;  i += 256) { int r = i >> 3, c = i & 7; sv1t[c*8+r]  = fcv_w1[i] * RS8; }
    for (int i = tid; i < 64;  i += 256) { int r = i >> 3, c = i & 7; sv2t[c*8+r]  = fcv_w2[i] * RS8; }
    __syncthreads();

    int e = blockIdx.x * 256 + tid;
    if (e >= NE) return;

    float es[16];
    {
        const float4* p = (const float4*)(edge_scalars + (size_t)e * 16);
        #pragma unroll
        for (int j = 0; j < 4; ++j) {
            float4 t = p[j];
            es[4*j+0]=t.x; es[4*j+1]=t.y; es[4*j+2]=t.z; es[4*j+3]=t.w;
        }
    }

    float hk[8], hv[8];
    mlp_hidden_t(es, sk0t, sk1t, sk2t, hk);
    mlp_hidden_t(es, sv0t, sv1t, sv2t, hv);

    float4 ea = *(const float4*)(edge_attr + (size_t)e * 4);
    int src = edge_src[e];
    int slot = pos[e];

    uint4 u0 = make_uint4(bf2(hk[0],hk[1]), bf2(hk[2],hk[3]), bf2(hk[4],hk[5]), bf2(hk[6],hk[7]));
    uint4 u1 = make_uint4(bf2(hv[0],hv[1]), bf2(hv[2],hv[3]), bf2(hv[4],hv[5]), bf2(hv[6],hv[7]));
    float4 f3 = make_float4(__int_as_float(src), 0.f, 0.f, 0.f);

    float* bp = blob + (size_t)slot * 16;
    *(uint4*)(bp + 0)  = u0;
    *(uint4*)(bp + 4)  = u1;
    *(float4*)(bp + 8) = ea;
    *(float4*)(bp + 12) = f3;
}

// ---------------- B: logit + v pass (block = 16 dst nodes, coalesced blob reads) ----------------
constexpr int NPB = 16;        // nodes per block
constexpr int RSTRIDE = 516;   // 512 + 4 pad

__global__ __launch_bounds__(256, 4) void logit_kernel(
    const int* __restrict__ offs,
    float* blob,                       // read hk/hv/ea/src, overwrite with exv*v (no restrict: aliased r/w)
    const float* __restrict__ nf, const float* __restrict__ qk,
    const float* __restrict__ fck_w3, const float* __restrict__ fcv_w3,
    float* __restrict__ ex_out)
{
    __shared__ float R[NPB * RSTRIDE];
    __shared__ float sv3t[512];
    __shared__ int soffs[NPB + 1];
    int tid = threadIdx.x;
    int nbase = blockIdx.x * NPB;

    for (int i = tid; i < 512; i += 256) {
        int h = i >> 6, u = (i >> 2) & 15, w = i & 3;
        sv3t[u * 32 + h * 4 + w] = fcv_w3[i] * (RS8 * 0.5f);  // * 1/sqrt(4)
    }
    if (tid < NPB + 1) {
        int nn = nbase + tid;
        soffs[tid] = (nn == 0) ? 0 : offs[nn - 1];
    }

    // R build: 16 nodes x 512 elems, 8 MAC each
    constexpr float S3 = RS8 * 0.125f;   // fck_w3 scale * 1/sqrt(64)
    for (int idx = tid; idx < NPB * 512; idx += 256) {
        int ln = idx >> 9;
        int j = idx & 511;                 // j = h*64 + (u*4+v)
        int h = j >> 6, uv = j & 63;
        const float4* w = (const float4*)(fck_w3 + h * 512 + uv * 8);
        float4 w0 = w[0], w1 = w[1];
        const float4* qp = (const float4*)(qk + (size_t)(nbase + ln) * 8);
        float4 q0 = qp[0], q1 = qp[1];
        float t = w0.x*q0.x + w0.y*q0.y + w0.z*q0.z + w0.w*q0.w
                + w1.x*q1.x + w1.y*q1.y + w1.z*q1.z + w1.w*q1.w;
        R[ln * RSTRIDE + j] = t * S3;
    }
    __syncthreads();

    int estart = soffs[0];
    int eend = soffs[NPB];

    for (int i = estart + tid; i < eend; i += 256) {
        // local node index: binary search in soffs (17 sorted entries, 2^4 = 16)
        int lo = 0, hi = NPB;
        #pragma unroll
        for (int s = 0; s < 4; ++s) {
            int mid = (lo + hi) >> 1;
            if (soffs[mid] <= i) lo = mid; else hi = mid;
        }
        int ln = lo;

        float* bp = blob + (size_t)i * 16;
        uint4 u0 = *(const uint4*)(bp + 0);
        uint4 u1 = *(const uint4*)(bp + 4);
        float4 ea4 = *(const float4*)(bp + 8);
        float4 f3 = *(const float4*)(bp + 12);
        int src = __float_as_int(f3.x);

        float hk[8], hv[8];
        hk[0]=bflo(u0.x); hk[1]=bfhi(u0.x); hk[2]=bflo(u0.y); hk[3]=bfhi(u0.y);
        hk[4]=bflo(u0.z); hk[5]=bfhi(u0.z); hk[6]=bflo(u0.w); hk[7]=bfhi(u0.w);
        hv[0]=bflo(u1.x); hv[1]=bfhi(u1.x); hv[2]=bflo(u1.y); hv[3]=bfhi(u1.y);
        hv[4]=bflo(u1.z); hv[5]=bfhi(u1.z); hv[6]=bflo(u1.w); hv[7]=bfhi(u1.w);
        float ea[4] = {ea4.x, ea4.y, ea4.z, ea4.w};

        float sf[16];
        {
            const float4* p = (const float4*)(nf + (size_t)src * 16);
            #pragma unroll
            for (int j = 0; j < 4; ++j) {
                float4 t = p[j];
                sf[4*j+0]=t.x; sf[4*j+1]=t.y; sf[4*j+2]=t.z; sf[4*j+3]=t.w;
            }
        }

        // x = sum_u sf[u] * sum_h hk[h] * dot(ea, R[ln][h][u][:])
        const float* Rb = &R[ln * RSTRIDE];
        float x = 0.f;
        #pragma unroll 4
        for (int u = 0; u < 16; ++u) {
            float xu = 0.f;
            #pragma unroll
            for (int h = 0; h < 8; ++h) {
                float4 r = *(const float4*)(Rb + (h * 16 + u) * 4);
                xu += hk[h] * (ea[0]*r.x + ea[1]*r.y + ea[2]*r.z + ea[3]*r.w);
            }
            x += sf[u] * xu;
        }

        float exv = __expf(x);
        ex_out[i] = exv;

        // overwrite blob with exv * v[u]  (v[u] = sf[u] * sum_h hv[h] * dot(ea, sv3t[u][h][:]))
        #pragma unroll
        for (int j = 0; j < 4; ++j) {
            float o[4];
            #pragma unroll
            for (int cc = 0; cc < 4; ++cc) {
                int u = 4*j + cc;
                float t = 0.f;
                #pragma unroll
                for (int h = 0; h < 8; ++h) {
                    float4 r = *(const float4*)(&sv3t[u * 32 + h * 4]);
                    t += hv[h] * (ea[0]*r.x + ea[1]*r.y + ea[2]*r.z + ea[3]*r.w);
                }
                o[cc] = exv * sf[u] * t;
            }
            *(float4*)(bp + 4*j) = make_float4(o[0], o[1], o[2], o[3]);
        }
    }
}

// ---------------- C: gather + output: out = sc + (Σ evs / Σ ex) @ W_lin2' ----------------
__global__ __launch_bounds__(256) void gather_out_kernel(
    const int* __restrict__ offs,
    const float* __restrict__ ex, const float* __restrict__ evs,
    const float* __restrict__ sc, const float* __restrict__ W_lin2,
    float* __restrict__ out)
{
    int wave = threadIdx.x >> 6;
    int L = threadIdx.x & 63;
    int n = blockIdx.x * 4 + wave;   // NN = 5000*4, all full
    int u = L & 15;
    int eo = L >> 4;

    int start = (n == 0) ? 0 : offs[n - 1];
    int end = offs[n];

    float accv = 0.f, accz = 0.f;
    for (int i = start + eo; i < end; i += 4)
        accv += evs[(size_t)i * 16 + u];          // 64B line per edge, 16-lane coalesced
    for (int i = start + L; i < end; i += 64)
        accz += ex[i];                            // fully coalesced

    accv += __shfl_xor(accv, 16);
    accv += __shfl_xor(accv, 32);
    #pragma unroll
    for (int s = 1; s < 64; s <<= 1) accz += __shfl_xor(accz, s);

    float den = (accz == 0.f) ? 1.f : accz;
    float a = 0.25f * accv / den;    // fold W_lin2's 1/sqrt(16)

    if (L < 16) {
        int c = L;
        float t = sc[(size_t)n * 16 + c];
        #pragma unroll
        for (int uu = 0; uu < 16; ++uu) {
            float au = __shfl(a, uu);
            t += au * W_lin2[uu * 16 + c];   // 1 KB table, L1-resident
        }
        out[(size_t)n * 16 + c] = t;
    }
}

} // namespace

extern "C" void kernel_launch(void* const* d_in, const int* in_sizes, int n_in,
                              void* d_out, int out_size, void* d_ws, size_t ws_size,
                              hipStream_t stream)
{
    const float* node_input   = (const float*)d_in[0];
    const float* node_attr    = (const float*)d_in[1];
    const int*   edge_src     = (const int*)d_in[2];
    const int*   edge_dst     = (const int*)d_in[3];
    const float* edge_attr    = (const float*)d_in[4];
    const float* edge_scalars = (const float*)d_in[5];
    const float* W_sc   = (const float*)d_in[6];
    const float* W_lin1 = (const float*)d_in[7];
    const float* W_hq   = (const float*)d_in[8];
    const float* fck_w0 = (const float*)d_in[9];
    const float* fck_w1 = (const float*)d_in[10];
    const float* fck_w2 = (const float*)d_in[11];
    const float* fck_w3 = (const float*)d_in[12];
    const float* fcv_w0 = (const float*)d_in[13];
    const float* fcv_w1 = (const float*)d_in[14];
    const float* fcv_w2 = (const float*)d_in[15];
    const float* fcv_w3 = (const float*)d_in[16];
    const float* W_dot  = (const float*)d_in[17];
    const float* W_lin2 = (const float*)d_in[18];

    float* ws  = (float*)d_ws;
    float* nf  = ws;                       // NN*16
    float* qk  = nf  + (size_t)NN * 16;    // NN*8
    float* sc  = qk  + (size_t)NN * 8;     // NN*16
    float* ex  = sc  + (size_t)NN * 16;    // NE
    float* blob = ex + NE;                 // NE*16 (hk/hv/ea/src -> then exv*v)
    int* counts = (int*)(blob + (size_t)NE * 16);  // NN
    int* offs   = counts + NN;                     // NN
    int* pos    = offs + NN;                       // NE

    hipMemsetAsync(counts, 0, (size_t)NN * sizeof(int), stream);

    const int EB = (NE + 255) / 256;   // 1563
    node_hist_kernel<<<EB, 256, 0, stream>>>(
        node_input, node_attr, edge_dst, W_sc, W_lin1, W_hq, W_dot, nf, qk, sc, counts);
    scan_kernel<<<1, 1024, 0, stream>>>(counts, offs);
    place_kernel<<<EB, 256, 0, stream>>>(edge_dst, offs, pos);
    edge_mlp_kernel<<<EB, 256, 0, stream>>>(
        pos, edge_src, edge_attr, edge_scalars,
        fck_w0, fck_w1, fck_w2, fcv_w0, fcv_w1, fcv_w2, blob);
    logit_kernel<<<NN / NPB, 256, 0, stream>>>(
        offs, blob, nf, qk, fck_w3, fcv_w3, ex);
    gather_out_kernel<<<NN / 4, 256, 0, stream>>>(
        offs, ex, blob, sc, W_lin2, (float*)d_out);
}

// Round 7
// 179.919 us; speedup vs baseline: 3.4459x; 3.4459x over previous
//
#include <hip/hip_runtime.h>
#include <math.h>

namespace {

constexpr int NN = 20000;   // nodes
constexpr int NE = 400000;  // edges

constexpr float RS8   = 0.35355339059327373f;  // 1/sqrt(8)
constexpr float RS128 = 0.08838834764831845f;  // 1/sqrt(128)

constexpr int BSTRIDE = 28;   // blob floats/slot: [0..3]=hk bf16x2, [4..7]=ea, [8..23]=v, [24]=src

__device__ __forceinline__ float silu_f(float x) {
    return x / (1.0f + __expf(-x));
}

// pack two floats as bf16 pair (RNE) into one uint
__device__ __forceinline__ unsigned int bf2(float a, float b) {
    unsigned int ua = __float_as_uint(a), ub = __float_as_uint(b);
    ua = (ua + 0x7FFFu + ((ua >> 16) & 1u)) >> 16;
    ub = (ub + 0x7FFFu + ((ub >> 16) & 1u)) >> 16;
    return (ub << 16) | ua;
}
__device__ __forceinline__ float bflo(unsigned int u) { return __uint_as_float(u << 16); }
__device__ __forceinline__ float bfhi(unsigned int u) { return __uint_as_float(u & 0xFFFF0000u); }

// ---------------- node + hist kernel: sc, nf, qk, counts ----------------
__global__ __launch_bounds__(256) void node_hist_kernel(
    const float* __restrict__ node_input, const float* __restrict__ node_attr,
    const int* __restrict__ edge_dst,
    const float* __restrict__ W_sc, const float* __restrict__ W_lin1,
    const float* __restrict__ W_hq, const float* __restrict__ W_dot,
    float* __restrict__ nf_out, float* __restrict__ qk_out, float* __restrict__ sc_out,
    int* __restrict__ counts)
{
    // histogram part (all blocks)
    int e = blockIdx.x * 256 + threadIdx.x;
    if (e < NE) atomicAdd(&counts[edge_dst[e]], 1);

    // node part (first 79 blocks only)
    if (blockIdx.x >= (NN + 255) / 256) return;

    __shared__ float sWsc[2048];   // [a][b][c] (16,8,16), scale folded
    __shared__ float sW1[256];     // [a][c] (16,16)
    __shared__ float sWq[128];     // [a][c] (16,8)
    __shared__ float sdot[64];     // [a][c] (8,8)
    for (int i = threadIdx.x; i < 2048; i += 256) sWsc[i] = W_sc[i] * RS128;
    if (threadIdx.x < 256) sW1[threadIdx.x] = W_lin1[threadIdx.x] * 0.25f;
    if (threadIdx.x < 128) sWq[threadIdx.x] = W_hq[threadIdx.x] * 0.25f;
    if (threadIdx.x < 64)  sdot[threadIdx.x] = W_dot[threadIdx.x] * 0.125f;  // 1/sqrt(64)
    __syncthreads();

    int n = blockIdx.x * 256 + threadIdx.x;
    if (n >= NN) return;

    float ni[16], na[8];
    {
        const float4* p = (const float4*)(node_input + (size_t)n * 16);
        #pragma unroll
        for (int j = 0; j < 4; ++j) {
            float4 t = p[j];
            ni[4*j+0]=t.x; ni[4*j+1]=t.y; ni[4*j+2]=t.z; ni[4*j+3]=t.w;
        }
        const float4* pa = (const float4*)(node_attr + (size_t)n * 8);
        #pragma unroll
        for (int j = 0; j < 2; ++j) {
            float4 t = pa[j];
            na[4*j+0]=t.x; na[4*j+1]=t.y; na[4*j+2]=t.z; na[4*j+3]=t.w;
        }
    }

    float sc[16];
    #pragma unroll
    for (int c = 0; c < 16; ++c) sc[c] = 0.f;
    #pragma unroll 4
    for (int a = 0; a < 16; ++a) {
        #pragma unroll
        for (int b = 0; b < 8; ++b) {
            float p = ni[a] * na[b];
            const float* w = &sWsc[(a * 8 + b) * 16];
            #pragma unroll
            for (int c = 0; c < 16; ++c) sc[c] += p * w[c];
        }
    }

    float nf[16];
    #pragma unroll
    for (int c = 0; c < 16; ++c) {
        float t = 0.f;
        #pragma unroll
        for (int a = 0; a < 16; ++a) t += ni[a] * sW1[a * 16 + c];
        nf[c] = t;
    }
    float q[8];
    #pragma unroll
    for (int c = 0; c < 8; ++c) {
        float t = 0.f;
        #pragma unroll
        for (int a = 0; a < 16; ++a) t += nf[a] * sWq[a * 8 + c];
        q[c] = t;
    }
    float qk[8];
    #pragma unroll
    for (int c = 0; c < 8; ++c) {
        float t = 0.f;
        #pragma unroll
        for (int a = 0; a < 8; ++a) t += q[a] * sdot[a * 8 + c];
        qk[c] = t;
    }

    float4* nfo = (float4*)(nf_out + (size_t)n * 16);
    #pragma unroll
    for (int j = 0; j < 4; ++j) nfo[j] = make_float4(nf[4*j], nf[4*j+1], nf[4*j+2], nf[4*j+3]);
    float4* qko = (float4*)(qk_out + (size_t)n * 8);
    #pragma unroll
    for (int j = 0; j < 2; ++j) qko[j] = make_float4(qk[4*j], qk[4*j+1], qk[4*j+2], qk[4*j+3]);
    float4* sco = (float4*)(sc_out + (size_t)n * 16);
    #pragma unroll
    for (int j = 0; j < 4; ++j) sco[j] = make_float4(sc[4*j], sc[4*j+1], sc[4*j+2], sc[4*j+3]);
}

// ---------------- scan: exclusive prefix of counts -> offs ----------------
__global__ __launch_bounds__(1024) void scan_kernel(
    const int* __restrict__ counts, int* __restrict__ offs)
{
    __shared__ int part[1024];
    int t = threadIdx.x;
    int base = t * 20;
    int s = 0;
    #pragma unroll 4
    for (int i = 0; i < 20; ++i) {
        int idx = base + i;
        if (idx < NN) s += counts[idx];
    }
    part[t] = s;
    __syncthreads();
    #pragma unroll
    for (int d = 1; d < 1024; d <<= 1) {
        int v = (t >= d) ? part[t - d] : 0;
        __syncthreads();
        part[t] += v;
        __syncthreads();
    }
    int run = part[t] - s;
    for (int i = 0; i < 20; ++i) {
        int idx = base + i;
        if (idx < NN) {
            offs[idx] = run;
            run += counts[idx];
        }
    }
}

// ---------------- placement: pos[e] = slot; offs becomes inclusive ----------------
__global__ __launch_bounds__(256) void place_kernel(
    const int* __restrict__ edge_dst, int* __restrict__ offs, int* __restrict__ pos)
{
    int e = blockIdx.x * 256 + threadIdx.x;
    if (e >= NE) return;
    int dst = edge_dst[e];
    pos[e] = atomicAdd(&offs[dst], 1);
}

// ---------------- MLP hiddens with transposed weights ----------------
__device__ __forceinline__ void mlp_hidden_t(const float es[16], const float* __restrict__ w0t,
                                             const float* __restrict__ w1t, const float* __restrict__ w2t,
                                             float out[8])
{
    float h0[8];
    #pragma unroll
    for (int j = 0; j < 8; ++j) {
        float t = 0.f;
        #pragma unroll
        for (int i = 0; i < 16; ++i) t += es[i] * w0t[j * 16 + i];
        h0[j] = silu_f(t);
    }
    float h1[8];
    #pragma unroll
    for (int j = 0; j < 8; ++j) {
        float t = 0.f;
        #pragma unroll
        for (int i = 0; i < 8; ++i) t += h0[i] * w1t[j * 8 + i];
        h1[j] = silu_f(t);
    }
    #pragma unroll
    for (int j = 0; j < 8; ++j) {
        float t = 0.f;
        #pragma unroll
        for (int i = 0; i < 8; ++i) t += h1[i] * w2t[j * 8 + i];
        out[j] = silu_f(t);
    }
}

// ---------------- A: MLP + v pass (natural edge order, coalesced reads) ----------------
__global__ __launch_bounds__(256) void edge_mlp_kernel(
    const int* __restrict__ pos, const int* __restrict__ edge_src,
    const float* __restrict__ edge_attr, const float* __restrict__ edge_scalars,
    const float* __restrict__ nf,
    const float* __restrict__ fck_w0, const float* __restrict__ fck_w1,
    const float* __restrict__ fck_w2,
    const float* __restrict__ fcv_w0, const float* __restrict__ fcv_w1,
    const float* __restrict__ fcv_w2, const float* __restrict__ fcv_w3,
    float* __restrict__ blob)
{
    __shared__ float sk0t[128], sk1t[64], sk2t[64];
    __shared__ float sv0t[128], sv1t[64], sv2t[64], sv3t[512];
    int tid = threadIdx.x;
    for (int i = tid; i < 128; i += 256) { int r = i >> 3, c = i & 7; sk0t[c*16+r] = fck_w0[i] * 0.25f; }
    for (int i = tid; i < 64;  i += 256) { int r = i >> 3, c = i & 7; sk1t[c*8+r]  = fck_w1[i] * RS8; }
    for (int i = tid; i < 64;  i += 256) { int r = i >> 3, c = i & 7; sk2t[c*8+r]  = fck_w2[i] * RS8; }
    for (int i = tid; i < 128; i += 256) { int r = i >> 3, c = i & 7; sv0t[c*16+r] = fcv_w0[i] * 0.25f; }
    for (int i = tid; i < 64;  i += 256) { int r = i >> 3, c = i & 7; sv1t[c*8+r]  = fcv_w1[i] * RS8; }
    for (int i = tid; i < 64;  i += 256) { int r = i >> 3, c = i & 7; sv2t[c*8+r]  = fcv_w2[i] * RS8; }
    for (int i = tid; i < 512; i += 256) {
        int h = i >> 6, u = (i >> 2) & 15, w = i & 3;
        sv3t[u * 32 + h * 4 + w] = fcv_w3[i] * (RS8 * 0.5f);  // * 1/sqrt(4)
    }
    __syncthreads();

    int e = blockIdx.x * 256 + tid;
    if (e >= NE) return;

    float es[16];
    {
        const float4* p = (const float4*)(edge_scalars + (size_t)e * 16);
        #pragma unroll
        for (int j = 0; j < 4; ++j) {
            float4 t = p[j];
            es[4*j+0]=t.x; es[4*j+1]=t.y; es[4*j+2]=t.z; es[4*j+3]=t.w;
        }
    }

    float hk[8], hv[8];
    mlp_hidden_t(es, sk0t, sk1t, sk2t, hk);
    mlp_hidden_t(es, sv0t, sv1t, sv2t, hv);

    float4 ea = *(const float4*)(edge_attr + (size_t)e * 4);
    int src = edge_src[e];
    float ea4[4] = {ea.x, ea.y, ea.z, ea.w};

    float sf[16];
    {
        const float4* p = (const float4*)(nf + (size_t)src * 16);
        #pragma unroll
        for (int j = 0; j < 4; ++j) {
            float4 t = p[j];
            sf[4*j+0]=t.x; sf[4*j+1]=t.y; sf[4*j+2]=t.z; sf[4*j+3]=t.w;
        }
    }

    int slot = pos[e];
    float* bp = blob + (size_t)slot * BSTRIDE;

    uint4 hku = make_uint4(bf2(hk[0],hk[1]), bf2(hk[2],hk[3]), bf2(hk[4],hk[5]), bf2(hk[6],hk[7]));
    *(uint4*)(bp + 0) = hku;
    *(float4*)(bp + 4) = ea;

    // v[u] = sf[u] * sum_h hv[h] * dot(ea, sv3t[u][h][:])  -> blob[8..23]
    #pragma unroll
    for (int j = 0; j < 4; ++j) {
        float o[4];
        #pragma unroll
        for (int cc = 0; cc < 4; ++cc) {
            int u = 4*j + cc;
            float t = 0.f;
            #pragma unroll
            for (int h = 0; h < 8; ++h) {
                const float4 r = *(const float4*)(&sv3t[u * 32 + h * 4]);
                t += hv[h] * (ea4[0]*r.x + ea4[1]*r.y + ea4[2]*r.z + ea4[3]*r.w);
            }
            o[cc] = sf[u] * t;
        }
        *(float4*)(bp + 8 + 4*j) = make_float4(o[0], o[1], o[2], o[3]);
    }
    bp[24] = __int_as_float(src);
}

// ---------------- B: fused logit + softmax-gather + output ----------------
// 1-wave block, 4 nodes. Prologue: R[ln][512] in LDS. Chunk loop:
//   phase 1: lane L computes x for edge-slot c0+L per-thread (LDS R broadcast), sx[L]=exp(x)
//   phase 2: 16-lane group g accumulates node g's  sum sx*v  and  sum sx.
__global__ __launch_bounds__(64) void fused_gather_kernel(
    const int* __restrict__ offs,
    const float* __restrict__ blob,
    const float* __restrict__ nf, const float* __restrict__ qk,
    const float* __restrict__ fck_w3,
    const float* __restrict__ sc, const float* __restrict__ W_lin2,
    float* __restrict__ out)
{
    constexpr int RSTRIDE = 516;
    __shared__ float R[4 * RSTRIDE];
    __shared__ float sx[64];
    __shared__ int soffs[5];

    int tid = threadIdx.x;
    int nbase = blockIdx.x * 4;          // NN = 5000*4

    if (tid < 5) {
        int nn = nbase + tid;
        soffs[tid] = (nn == 0) ? 0 : offs[nn - 1];
    }

    // R build: 4 nodes x 512 elems, 8 MAC each (fck_w3 L1/L2-resident, coalesced 32B/lane)
    constexpr float S3 = RS8 * 0.125f;   // fck_w3 scale * 1/sqrt(64)
    #pragma unroll 4
    for (int idx = tid; idx < 4 * 512; idx += 64) {
        int ln = idx >> 9;
        int j = idx & 511;               // j = h*64 + u*4 + v
        int h = j >> 6, uv = j & 63;
        const float4* w = (const float4*)(fck_w3 + h * 512 + uv * 8);
        float4 w0 = w[0], w1 = w[1];
        const float4* qp = (const float4*)(qk + (size_t)(nbase + ln) * 8);
        float4 q0 = qp[0], q1 = qp[1];
        float t = w0.x*q0.x + w0.y*q0.y + w0.z*q0.z + w0.w*q0.w
                + w1.x*q1.x + w1.y*q1.y + w1.z*q1.z + w1.w*q1.w;
        R[ln * RSTRIDE + j] = t * S3;
    }
    __syncthreads();

    int g = tid >> 4;
    int u = tid & 15;
    int s0 = soffs[0], s4 = soffs[4];
    int gs = soffs[g], ge = soffs[g + 1];

    float accv = 0.f, accz = 0.f;
    for (int c0 = s0; c0 < s4; c0 += 64) {
        // phase 1: per-thread logit for edge slot c0+tid
        int i = c0 + tid;
        if (i < s4) {
            int ln = (i >= soffs[2]) ? 2 : 0;
            ln += (i >= soffs[ln + 1]) ? 1 : 0;

            const float* bp = blob + (size_t)i * BSTRIDE;
            uint4 hku = *(const uint4*)(bp + 0);
            float4 ea = *(const float4*)(bp + 4);
            int src = __float_as_int(bp[24]);

            float hk[8];
            hk[0]=bflo(hku.x); hk[1]=bfhi(hku.x); hk[2]=bflo(hku.y); hk[3]=bfhi(hku.y);
            hk[4]=bflo(hku.z); hk[5]=bfhi(hku.z); hk[6]=bflo(hku.w); hk[7]=bfhi(hku.w);

            float sf[16];
            {
                const float4* p = (const float4*)(nf + (size_t)src * 16);
                #pragma unroll
                for (int j = 0; j < 4; ++j) {
                    float4 t = p[j];
                    sf[4*j+0]=t.x; sf[4*j+1]=t.y; sf[4*j+2]=t.z; sf[4*j+3]=t.w;
                }
            }

            const float* Rb = &R[ln * RSTRIDE];
            float x = 0.f;
            #pragma unroll 4
            for (int uu = 0; uu < 16; ++uu) {
                float xu = 0.f;
                #pragma unroll
                for (int h = 0; h < 8; ++h) {
                    const float4 r = *(const float4*)(Rb + h * 64 + uu * 4);
                    xu += hk[h] * (ea.x*r.x + ea.y*r.y + ea.z*r.z + ea.w*r.w);
                }
                x += sf[uu] * xu;
            }
            sx[tid] = __expf(x);
        }
        __syncthreads();

        // phase 2: group g accumulates its node's slots within this chunk
        int js = (gs > c0) ? gs : c0;
        int je0 = c0 + 64;
        int je = (ge < je0) ? ge : je0;
        for (int j = js; j < je; ++j) {
            float s = sx[j - c0];
            accv += s * blob[(size_t)j * BSTRIDE + 8 + u];   // 64B line, 16-lane coalesced
            accz += s;
        }
        __syncthreads();
    }

    float den = (accz == 0.f) ? 1.f : accz;
    float a = 0.25f * accv / den;        // fold W_lin2's 1/sqrt(16)

    // epilogue: lane (g,u) -> out[nbase+g][u]
    float t = sc[(size_t)nbase * 16 + tid];
    #pragma unroll
    for (int uu = 0; uu < 16; ++uu) {
        float au = __shfl(a, g * 16 + uu);
        t += au * W_lin2[uu * 16 + u];   // 1 KB table, L1-resident
    }
    out[(size_t)nbase * 16 + tid] = t;
}

} // namespace

extern "C" void kernel_launch(void* const* d_in, const int* in_sizes, int n_in,
                              void* d_out, int out_size, void* d_ws, size_t ws_size,
                              hipStream_t stream)
{
    const float* node_input   = (const float*)d_in[0];
    const float* node_attr    = (const float*)d_in[1];
    const int*   edge_src     = (const int*)d_in[2];
    const int*   edge_dst     = (const int*)d_in[3];
    const float* edge_attr    = (const float*)d_in[4];
    const float* edge_scalars = (const float*)d_in[5];
    const float* W_sc   = (const float*)d_in[6];
    const float* W_lin1 = (const float*)d_in[7];
    const float* W_hq   = (const float*)d_in[8];
    const float* fck_w0 = (const float*)d_in[9];
    const float* fck_w1 = (const float*)d_in[10];
    const float* fck_w2 = (const float*)d_in[11];
    const float* fck_w3 = (const float*)d_in[12];
    const float* fcv_w0 = (const float*)d_in[13];
    const float* fcv_w1 = (const float*)d_in[14];
    const float* fcv_w2 = (const float*)d_in[15];
    const float* fcv_w3 = (const float*)d_in[16];
    const float* W_dot  = (const float*)d_in[17];
    const float* W_lin2 = (const float*)d_in[18];

    float* ws  = (float*)d_ws;
    float* nf  = ws;                       // NN*16
    float* qk  = nf  + (size_t)NN * 16;    // NN*8
    float* sc  = qk  + (size_t)NN * 8;     // NN*16
    float* blob = sc + (size_t)NN * 16;    // NE*28
    int* counts = (int*)(blob + (size_t)NE * BSTRIDE);  // NN
    int* offs   = counts + NN;                          // NN
    int* pos    = offs + NN;                            // NE

    hipMemsetAsync(counts, 0, (size_t)NN * sizeof(int), stream);

    const int EB = (NE + 255) / 256;   // 1563
    node_hist_kernel<<<EB, 256, 0, stream>>>(
        node_input, node_attr, edge_dst, W_sc, W_lin1, W_hq, W_dot, nf, qk, sc, counts);
    scan_kernel<<<1, 1024, 0, stream>>>(counts, offs);
    place_kernel<<<EB, 256, 0, stream>>>(edge_dst, offs, pos);
    edge_mlp_kernel<<<EB, 256, 0, stream>>>(
        pos, edge_src, edge_attr, edge_scalars, nf,
        fck_w0, fck_w1, fck_w2, fcv_w0, fcv_w1, fcv_w2, fcv_w3, blob);
    fused_gather_kernel<<<NN / 4, 64, 0, stream>>>(
        offs, blob, nf, qk, fck_w3, sc, W_lin2, (float*)d_out);
}